// Round 1
// 5191.089 us; speedup vs baseline: 1.5562x; 1.5562x over previous
//
#include <hip/hip_runtime.h>
#include <cmath>

#define B_ 256
#define F_ 2048
#define T_ 40
#define V_ 10000
#define L_ 20
#define ATTR_ 400
#define E_ 512
#define H_ 1024
#define A_ 512
#define NS_ 19

typedef float f32x4 __attribute__((ext_vector_type(4)));
typedef short bf16x8 __attribute__((ext_vector_type(8)));

__device__ __forceinline__ float sigm(float x) { return 1.0f / (1.0f + expf(-x)); }

// split-bf16 helpers: x ~= hi + lo, each bf16 (RNE). residual ~2^-18 * |x|
__device__ __forceinline__ unsigned short f2bf(float x) {
    unsigned int u = __float_as_uint(x);
    u += 0x7fffu + ((u >> 16) & 1u);
    return (unsigned short)(u >> 16);
}
__device__ __forceinline__ float bf2f(unsigned short h) {
    return __uint_as_float(((unsigned int)h) << 16);
}
__device__ __forceinline__ void gload16(const void* g, void* l) {
    __builtin_amdgcn_global_load_lds(
        (const __attribute__((address_space(1))) unsigned int*)g,
        (__attribute__((address_space(3))) unsigned int*)l, 16, 0, 0);
}
__device__ __forceinline__ f32x4 mfma16(bf16x8 a, bf16x8 b, f32x4 c) {
    return __builtin_amdgcn_mfma_f32_16x16x32_bf16(a, b, c, 0, 0, 0);
}

// ---------------------------------------------------------------------------
// Split-bf16 MFMA GEMM.  C[b][m] = sum_k A[m][k]*B[b][k]  (A=weights, B=acts,
// both row-major k-contiguous bf16 hi/lo planes).  Tile 128m x 128b, 4 waves,
// per-wave 64x64 via 4x4 frags of v_mfma_f32_16x16x32_bf16 (3 products:
// hh + hl + lh).  blockIdx.z selects an independent K-chunk; partials land in
// out + z*zstride (DIRECT=0) or directly with bias[m] (DIRECT=1, z==0).
// LDS layout [plane][blk16][kgrp][16][8]: both global_load_lds staging and
// ds_read_b128 frag reads are perfectly linear -> conflict-free.
// ---------------------------------------------------------------------------
struct GChunk {
    const unsigned short* Ahi; const unsigned short* Alo;
    const unsigned short* Bhi; const unsigned short* Blo;
    int lda, ldb, kc;
};
struct GChunks { GChunk c[8]; };

template<int DIRECT>
__global__ __launch_bounds__(256) void gemm_mfma(
    GChunks ch, float* __restrict__ out, const float* __restrict__ bias,
    int Mreal, int ldc, long zstride)
{
    const GChunk cc = ch.c[blockIdx.z];
    const int tid  = threadIdx.x;
    const int lane = tid & 63;
    const int w    = tid >> 6;
    const int m0   = blockIdx.x * 128;
    const int n0   = blockIdx.y * 128;
    const int kg   = lane >> 4;
    const int rr   = lane & 15;

    __shared__ __align__(16) unsigned short As[2][8][4][16][8];
    __shared__ __align__(16) unsigned short Bs[2][8][4][16][8];

    int ar0 = m0 + w * 32 + rr;
    int ar1 = ar0 + 16;
    if (ar0 >= Mreal) ar0 = Mreal - 1;
    if (ar1 >= Mreal) ar1 = Mreal - 1;
    const int br0 = n0 + w * 32 + rr;
    const int br1 = br0 + 16;

    const unsigned short* pAh0 = cc.Ahi + (long)ar0 * cc.lda + kg * 8;
    const unsigned short* pAh1 = cc.Ahi + (long)ar1 * cc.lda + kg * 8;
    const unsigned short* pAl0 = cc.Alo + (long)ar0 * cc.lda + kg * 8;
    const unsigned short* pAl1 = cc.Alo + (long)ar1 * cc.lda + kg * 8;
    const unsigned short* pBh0 = cc.Bhi + (long)br0 * cc.ldb + kg * 8;
    const unsigned short* pBh1 = cc.Bhi + (long)br1 * cc.ldb + kg * 8;
    const unsigned short* pBl0 = cc.Blo + (long)br0 * cc.ldb + kg * 8;
    const unsigned short* pBl1 = cc.Blo + (long)br1 * cc.ldb + kg * 8;

    unsigned short* dAh0 = &As[0][w*2  ][0][0][0];
    unsigned short* dAh1 = &As[0][w*2+1][0][0][0];
    unsigned short* dAl0 = &As[1][w*2  ][0][0][0];
    unsigned short* dAl1 = &As[1][w*2+1][0][0][0];
    unsigned short* dBh0 = &Bs[0][w*2  ][0][0][0];
    unsigned short* dBh1 = &Bs[0][w*2+1][0][0][0];
    unsigned short* dBl0 = &Bs[1][w*2  ][0][0][0];
    unsigned short* dBl1 = &Bs[1][w*2+1][0][0][0];

    const int amb = (w >> 1) * 4;
    const int bnb = (w & 1) * 4;

    f32x4 zero4 = {0.f, 0.f, 0.f, 0.f};
    f32x4 acc[4][4];
#pragma unroll
    for (int i = 0; i < 4; ++i)
#pragma unroll
        for (int j = 0; j < 4; ++j) acc[i][j] = zero4;

    const int kst = cc.kc >> 5;
    for (int ks = 0; ks < kst; ++ks) {
        gload16(pAh0, dAh0); gload16(pAh1, dAh1);
        gload16(pAl0, dAl0); gload16(pAl1, dAl1);
        gload16(pBh0, dBh0); gload16(pBh1, dBh1);
        gload16(pBl0, dBl0); gload16(pBl1, dBl1);
        pAh0 += 32; pAh1 += 32; pAl0 += 32; pAl1 += 32;
        pBh0 += 32; pBh1 += 32; pBl0 += 32; pBl1 += 32;
        __syncthreads();   // drains vmcnt -> staged data visible
        bf16x8 ah[4], al[4], bh[4], bl[4];
#pragma unroll
        for (int i = 0; i < 4; ++i) {
            ah[i] = *(const bf16x8*)&As[0][amb + i][kg][rr][0];
            al[i] = *(const bf16x8*)&As[1][amb + i][kg][rr][0];
            bh[i] = *(const bf16x8*)&Bs[0][bnb + i][kg][rr][0];
            bl[i] = *(const bf16x8*)&Bs[1][bnb + i][kg][rr][0];
        }
#pragma unroll
        for (int i = 0; i < 4; ++i)
#pragma unroll
            for (int j = 0; j < 4; ++j) {
                acc[i][j] = mfma16(ah[i], bh[j], acc[i][j]);
                acc[i][j] = mfma16(ah[i], bl[j], acc[i][j]);
                acc[i][j] = mfma16(al[i], bh[j], acc[i][j]);
            }
        __syncthreads();   // reads done before next stage overwrites
    }

    const int wm = (w >> 1) * 64;
    const int wn = (w & 1) * 64;
    const int mr = (lane >> 4) * 4;
    const int ncl = lane & 15;
    float* P = DIRECT ? out : out + (long)blockIdx.z * zstride;
#pragma unroll
    for (int i = 0; i < 4; ++i) {
        int mm = m0 + wm + i * 16 + mr;
        if (mm < Mreal) {
            float4 bv = {0.f, 0.f, 0.f, 0.f};
            if (DIRECT && bias) bv = *(const float4*)&bias[mm];
#pragma unroll
            for (int j = 0; j < 4; ++j) {
                int bb = n0 + wn + j * 16 + ncl;
                float4 v;
                v.x = acc[i][j].x + bv.x;
                v.y = acc[i][j].y + bv.y;
                v.z = acc[i][j].z + bv.z;
                v.w = acc[i][j].w + bv.w;
                *(float4*)&P[(long)bb * ldc + mm] = v;
            }
        }
    }
}

// fused split-K reduce + LSTM elementwise.  P layout [z][b][4096] (i|f|g|o).
// bmode 1: base[b][4096] (precomputed mean-feature term incl. biases)
// bmode 2: base[n] broadcast bias vector
__global__ __launch_bounds__(256) void lstm_fused(
    const float* __restrict__ P, int nz, long zstride,
    const float* __restrict__ base, int bmode,
    float* __restrict__ c,
    unsigned short* __restrict__ hhi, unsigned short* __restrict__ hlo)
{
    int idx = blockIdx.x * 256 + threadIdx.x;
    int n = idx & 1023;
    long r = ((long)(idx >> 10)) * 4096 + n;
    float ig = 0.f, fg = 0.f, gg = 0.f, og = 0.f;
    for (int z = 0; z < nz; ++z) {
        const float* p = P + (long)z * zstride + r;
        ig += p[0]; fg += p[1024]; gg += p[2048]; og += p[3072];
    }
    if (bmode == 1) {
        const float* q = base + r;
        ig += q[0]; fg += q[1024]; gg += q[2048]; og += q[3072];
    } else {
        ig += base[n]; fg += base[1024 + n]; gg += base[2048 + n]; og += base[3072 + n];
    }
    float cn = sigm(fg) * c[idx] + sigm(ig) * tanhf(gg);
    c[idx] = cn;
    float hv = sigm(og) * tanhf(cn);
    unsigned short hi = f2bf(hv);
    hhi[idx] = hi;
    hlo[idx] = f2bf(hv - bf2f(hi));
}

// fused attention: eh split-K reduce -> scores -> softmax -> v_hat (-> hi/lo)
__global__ __launch_bounds__(256) void attention_kernel(
    const float* __restrict__ ef, const float* __restrict__ Pe,
    const float* __restrict__ feats, const float* __restrict__ atta_W,
    const float* __restrict__ atta_b,
    unsigned short* __restrict__ vhhi, unsigned short* __restrict__ vhlo)
{
    __shared__ float eh_s[512], aw_s[512], sc_s[48];
    int b = blockIdx.x, tid = threadIdx.x;
    float e0 = 0.f, e1 = 0.f;
#pragma unroll
    for (int z = 0; z < 8; ++z) {
        const float* p = Pe + (long)z * (512 * 256) + b * 512;
        e0 += p[tid]; e1 += p[tid + 256];
    }
    eh_s[tid] = e0; eh_s[tid + 256] = e1;
    aw_s[tid] = atta_W[tid]; aw_s[tid + 256] = atta_W[tid + 256];
    __syncthreads();
    int w = tid >> 6, lane = tid & 63;
    float ab0 = atta_b[0];
    for (int i = 0; i < 10; ++i) {
        int t = w * 10 + i;
        const float* ep = ef + ((long)b * T_ + t) * A_ + lane * 8;
        float4 e1v = *(const float4*)ep;
        float4 e2v = *(const float4*)(ep + 4);
        int a = lane * 8;
        float s = tanhf(e1v.x + eh_s[a+0]) * aw_s[a+0] + tanhf(e1v.y + eh_s[a+1]) * aw_s[a+1]
                + tanhf(e1v.z + eh_s[a+2]) * aw_s[a+2] + tanhf(e1v.w + eh_s[a+3]) * aw_s[a+3]
                + tanhf(e2v.x + eh_s[a+4]) * aw_s[a+4] + tanhf(e2v.y + eh_s[a+5]) * aw_s[a+5]
                + tanhf(e2v.z + eh_s[a+6]) * aw_s[a+6] + tanhf(e2v.w + eh_s[a+7]) * aw_s[a+7];
#pragma unroll
        for (int o = 32; o > 0; o >>= 1) s += __shfl_down(s, o, 64);
        if (lane == 0) sc_s[t] = s + ab0;
    }
    __syncthreads();
    if (tid < 64) {
        float v = (tid < T_) ? sc_s[tid] : -INFINITY;
        float m = v;
#pragma unroll
        for (int o = 32; o > 0; o >>= 1) m = fmaxf(m, __shfl_down(m, o, 64));
        m = __shfl(m, 0, 64);
        float e = (tid < T_) ? expf(v - m) : 0.f;
        float su = e;
#pragma unroll
        for (int o = 32; o > 0; o >>= 1) su += __shfl_down(su, o, 64);
        su = __shfl(su, 0, 64);
        if (tid < T_) sc_s[tid] = e / su;
    }
    __syncthreads();
    for (int cc = 0; cc < 8; ++cc) {
        int f = cc * 256 + tid;
        const float* fp = feats + ((long)b * F_ + f) * T_;
        float acc = 0.f;
#pragma unroll
        for (int t4 = 0; t4 < 10; ++t4) {
            float4 v = *(const float4*)(fp + t4 * 4);
            acc += sc_s[t4*4+0] * v.x + sc_s[t4*4+1] * v.y
                 + sc_s[t4*4+2] * v.z + sc_s[t4*4+3] * v.w;
        }
        unsigned short hi = f2bf(acc);
        vhhi[(long)b * F_ + f] = hi;
        vhlo[(long)b * F_ + f] = f2bf(acc - bf2f(hi));
    }
}

// out[e] = sum_z P[z*zstride+e] + base[e & mask]
__global__ void reduce_rows(float* __restrict__ out, const float* __restrict__ P,
                            const float* __restrict__ base, int S, long zstride,
                            int n, int mask)
{
    long e = ((long)blockIdx.x * 256 + threadIdx.x) * 4;
    if (e >= n) return;
    float4 s = *(const float4*)&P[e];
    for (int z = 1; z < S; ++z) {
        float4 p = *(const float4*)&P[(long)z * zstride + e];
        s.x += p.x; s.y += p.y; s.z += p.z; s.w += p.w;
    }
    if (base) {
        float4 bv = *(const float4*)&base[e & mask];
        s.x += bv.x; s.y += bv.y; s.z += bv.z; s.w += bv.w;
    }
    *(float4*)&out[e] = s;
}

// preds[b][s][v] = P0 + P1 + prob_b   (P layout [z][b][10048])
__global__ void reduce_prob(const float* __restrict__ P, const float* __restrict__ pb,
                            float* __restrict__ dout, int s)
{
    int g = blockIdx.x * 256 + threadIdx.x;
    int b = g / 2500;
    int v = (g - b * 2500) * 4;
    float4 a = *(const float4*)&P[(long)b * 10048 + v];
    float4 c = *(const float4*)&P[256L * 10048 + (long)b * 10048 + v];
    float4 bb = *(const float4*)&pb[v];
    float4 r = {a.x + c.x + bb.x, a.y + c.y + bb.y, a.z + c.z + bb.z, a.w + c.w + bb.w};
    *(float4*)&dout[4864L + (long)b * (NS_ * (long)V_) + (long)s * V_ + v] = r;
}

// cast fp32 slice -> bf16 hi/lo, with optional zero-padded columns
__global__ void cast_slice(const float* __restrict__ src,
    unsigned short* __restrict__ dhi, unsigned short* __restrict__ dlo,
    int srcld, int scol0, int nvalid, int nwrite, int dld, int dcol0)
{
    int col = blockIdx.x * 256 + threadIdx.x;
    if (col >= nwrite) return;
    long row = blockIdx.y;
    float v = (col < nvalid) ? src[row * srcld + scol0 + col] : 0.f;
    unsigned short hi = f2bf(v);
    long o = row * dld + dcol0 + col;
    dhi[o] = hi; dlo[o] = f2bf(v - bf2f(hi));
}

__global__ void mean_cast(const float* __restrict__ feats,
                          unsigned short* __restrict__ mh, unsigned short* __restrict__ ml)
{
    int idx = blockIdx.x * 256 + threadIdx.x;
    const float* p = feats + (long)idx * T_;
    float s = 0.f;
#pragma unroll
    for (int t = 0; t < T_; t += 4) {
        float4 v = *(const float4*)(p + t);
        s += v.x + v.y + v.z + v.w;
    }
    s *= (1.0f / (float)T_);
    unsigned short hi = f2bf(s);
    mh[idx] = hi; ml[idx] = f2bf(s - bf2f(hi));
}

// feats[b][f][t] -> featsT[(b*40+t)][f] bf16 hi/lo
__global__ __launch_bounds__(256) void transpose_cast_feats(
    const float* __restrict__ feats,
    unsigned short* __restrict__ fh, unsigned short* __restrict__ fl)
{
    __shared__ float tf[2560];
    int b = blockIdx.y, f0 = blockIdx.x * 64;
    const float* src = feats + (long)b * (F_ * T_) + (long)f0 * T_;
#pragma unroll
    for (int q = 0; q < 10; ++q) tf[q * 256 + threadIdx.x] = src[q * 256 + threadIdx.x];
    __syncthreads();
#pragma unroll
    for (int q = 0; q < 10; ++q) {
        int idx = q * 256 + threadIdx.x;
        int t = idx >> 6, f = idx & 63;
        float v = tf[f * 40 + t];
        unsigned short hi = f2bf(v);
        long o = ((long)b * T_ + t) * F_ + f0 + f;
        fh[o] = hi; fl[o] = f2bf(v - bf2f(hi));
    }
}

__global__ void wv_gather_cast(const int* __restrict__ sents, const float* __restrict__ emb,
    unsigned short* __restrict__ wh, unsigned short* __restrict__ wl, int s)
{
    int idx = blockIdx.x * 256 + threadIdx.x;   // b*512 + e
    int b = idx >> 9, e = idx & 511;
    int wd = sents[b * L_ + s];
    float v = emb[(long)wd * E_ + e];
    unsigned short hi = f2bf(v);
    wh[idx] = hi; wl[idx] = f2bf(v - bf2f(hi));
}

__global__ void vec_add_kernel(const float* a, const float* b, float* out, int n)
{
    int i = blockIdx.x * 256 + threadIdx.x;
    if (i < n) out[i] = a[i] + b[i];
}

__global__ __launch_bounds__(256) void argmax_kernel(
    const float* __restrict__ dout_preds, float* __restrict__ outw, int s)
{
    __shared__ float sv[256];
    __shared__ int   si[256];
    int b = blockIdx.x, tid = threadIdx.x;
    const float* row = dout_preds + (long)b * (NS_ * (long)V_) + (long)s * V_;
    float best = -INFINITY; int bi = 0x7fffffff;
    for (int v = tid; v < V_; v += 256) {
        float x = row[v];
        if (x > best) { best = x; bi = v; }
    }
    sv[tid] = best; si[tid] = bi;
    __syncthreads();
    for (int o = 128; o > 0; o >>= 1) {
        if (tid < o) {
            float ov = sv[tid + o]; int oi = si[tid + o];
            if (ov > sv[tid] || (ov == sv[tid] && oi < si[tid])) { sv[tid] = ov; si[tid] = oi; }
        }
        __syncthreads();
    }
    if (tid == 0) outw[b * NS_ + s] = (float)si[0];
}

extern "C" void kernel_launch(void* const* d_in, const int* in_sizes, int n_in,
                              void* d_out, int out_size, void* d_ws, size_t ws_size,
                              hipStream_t stream)
{
    (void)in_sizes; (void)n_in; (void)out_size; (void)ws_size;
    const float* feats  = (const float*)d_in[0];
    const float* atts   = (const float*)d_in[1];
    const int*   sents  = (const int*)d_in[2];
    const float* attr_W = (const float*)d_in[3];
    const float* attr_b = (const float*)d_in[4];
    const float* emb    = (const float*)d_in[5];
    const float* l1_Wih = (const float*)d_in[6];
    const float* l1_Whh = (const float*)d_in[7];
    const float* l1_bih = (const float*)d_in[8];
    const float* l1_bhh = (const float*)d_in[9];
    const float* l2_Wih = (const float*)d_in[10];
    const float* l2_Whh = (const float*)d_in[11];
    const float* l2_bih = (const float*)d_in[12];
    const float* l2_bhh = (const float*)d_in[13];
    const float* prob_W = (const float*)d_in[14];
    const float* prob_b = (const float*)d_in[15];
    const float* attf_W = (const float*)d_in[16];
    const float* attf_b = (const float*)d_in[17];
    const float* atth_W = (const float*)d_in[18];
    const float* atth_b = (const float*)d_in[19];
    const float* atta_W = (const float*)d_in[20];
    const float* atta_b = (const float*)d_in[21];

    float* out = (float*)d_out;
    float* preds = out + B_ * NS_;

    char* pp = (char*)d_ws;
    auto alloc = [&](size_t n) { char* r = pp; pp += (n + 255) & ~(size_t)255; return r; };

    // region R: featsT (precompute only) overlaid later by W2ih + W1ih-mid
    char* R = alloc(83886080UL);
    unsigned short* fTh   = (unsigned short*)R;
    unsigned short* fTl   = (unsigned short*)(R + 41943040UL);
    unsigned short* W2ihh = (unsigned short*)R;
    unsigned short* W2ihl = (unsigned short*)(R + 25165824UL);
    unsigned short* Wmh   = (unsigned short*)(R + 50331648UL);
    unsigned short* Wml   = (unsigned short*)(R + 67108864UL);

    unsigned short* W1ph  = (unsigned short*)alloc(4096L*1536*2);  // Wih cols [0:1024)++[3072:3584)
    unsigned short* W1pl  = (unsigned short*)alloc(4096L*1536*2);
    unsigned short* W1hhh = (unsigned short*)alloc(4096L*1024*2);
    unsigned short* W1hhl = (unsigned short*)alloc(4096L*1024*2);
    unsigned short* W2hhh = (unsigned short*)alloc(4096L*1024*2);
    unsigned short* W2hhl = (unsigned short*)alloc(4096L*1024*2);
    unsigned short* Wprh  = (unsigned short*)alloc(10000L*1024*2);
    unsigned short* Wprl  = (unsigned short*)alloc(10000L*1024*2);
    unsigned short* Wahh  = (unsigned short*)alloc(512L*1024*2);
    unsigned short* Wahl  = (unsigned short*)alloc(512L*1024*2);
    unsigned short* Wafh  = (unsigned short*)alloc(512L*2048*2);
    unsigned short* Wafl  = (unsigned short*)alloc(512L*2048*2);
    unsigned short* Warh  = (unsigned short*)alloc(3072L*416*2);
    unsigned short* Warl  = (unsigned short*)alloc(3072L*416*2);

    float* ef    = (float*)alloc(10240L*512*4);
    float* base1 = (float*)alloc(4096L*256*4);
    float* Pbuf  = (float*)alloc(5L*4096*256*4);
    float* attrv = Pbuf;                          // temporal overlay

    unsigned short* h1h = (unsigned short*)alloc(256L*1024*2);
    unsigned short* h1l = (unsigned short*)alloc(256L*1024*2);
    unsigned short* h2h = (unsigned short*)alloc(256L*1024*2);
    unsigned short* h2l = (unsigned short*)alloc(256L*1024*2);
    unsigned short* wvh = (unsigned short*)alloc(256L*512*2);
    unsigned short* wvl = (unsigned short*)alloc(256L*512*2);
    unsigned short* vhh = (unsigned short*)alloc(256L*2048*2);
    unsigned short* vhl = (unsigned short*)alloc(256L*2048*2);
    unsigned short* mfh = (unsigned short*)alloc(256L*2048*2);
    unsigned short* mfl = (unsigned short*)alloc(256L*2048*2);
    unsigned short* attsh = (unsigned short*)alloc(256L*416*2);
    unsigned short* attsl = (unsigned short*)alloc(256L*416*2);
    unsigned short* avh = (unsigned short*)alloc(256L*3072*2);
    unsigned short* avl = (unsigned short*)alloc(256L*3072*2);
    float* c1 = (float*)alloc(256L*1024*4);
    float* c2 = (float*)alloc(256L*1024*4);
    float* bihbhh1 = (float*)alloc(4096*4);
    float* bias2   = (float*)alloc(4096*4);
    float* efbias  = (float*)alloc(512*4);

    // ---- one-time precompute ----
    hipMemsetAsync(c1, 0, 256L*1024*4, stream);
    hipMemsetAsync(c2, 0, 256L*1024*4, stream);
    hipMemsetAsync(h1h, 0, 256L*1024*2, stream);   // bf16(0) == 0x0000
    hipMemsetAsync(h1l, 0, 256L*1024*2, stream);

    vec_add_kernel<<<16, 256, 0, stream>>>(l1_bih, l1_bhh, bihbhh1, 4096);
    vec_add_kernel<<<16, 256, 0, stream>>>(l2_bih, l2_bhh, bias2, 4096);
    vec_add_kernel<<<2, 256, 0, stream>>>(attf_b, atth_b, efbias, 512);
    mean_cast<<<2048, 256, 0, stream>>>(feats, mfh, mfl);

    // weight casts outside region R
    cast_slice<<<dim3(4,4096), 256, 0, stream>>>(l1_Wih, W1ph, W1pl, 3584, 0,    1024, 1024, 1536, 0);
    cast_slice<<<dim3(2,4096), 256, 0, stream>>>(l1_Wih, W1ph, W1pl, 3584, 3072, 512,  512,  1536, 1024);
    cast_slice<<<dim3(4,4096), 256, 0, stream>>>(l1_Whh, W1hhh, W1hhl, 1024, 0, 1024, 1024, 1024, 0);
    cast_slice<<<dim3(4,4096), 256, 0, stream>>>(l2_Whh, W2hhh, W2hhl, 1024, 0, 1024, 1024, 1024, 0);
    cast_slice<<<dim3(4,10000), 256, 0, stream>>>(prob_W, Wprh, Wprl, 1024, 0, 1024, 1024, 1024, 0);
    cast_slice<<<dim3(4,512), 256, 0, stream>>>(atth_W, Wahh, Wahl, 1024, 0, 1024, 1024, 1024, 0);
    cast_slice<<<dim3(8,512), 256, 0, stream>>>(attf_W, Wafh, Wafl, 2048, 0, 2048, 2048, 2048, 0);
    cast_slice<<<dim3(2,3072), 256, 0, stream>>>(attr_W, Warh, Warl, 400, 0, 400, 416, 416, 0);
    cast_slice<<<dim3(2,256), 256, 0, stream>>>(atts, attsh, attsl, 400, 0, 400, 416, 416, 0);

    // embedf: ef[(b,t)][a] = featsT @ attf_W.T + (attf_b + atth_b)
    transpose_cast_feats<<<dim3(32,256), 256, 0, stream>>>(feats, fTh, fTl);
    {
        GChunks ch = {};
        ch.c[0] = {Wafh, Wafl, fTh, fTl, 2048, 2048, 2048};
        gemm_mfma<1><<<dim3(4,80,1), 256, 0, stream>>>(ch, ef, efbias, 512, 512, 0);
    }
    // attr_v = atts @ attr_W.T + attr_b  (K padded 400->416 with zeros)
    {
        GChunks ch = {};
        ch.c[0] = {Warh, Warl, attsh, attsl, 416, 416, 416};
        gemm_mfma<1><<<dim3(24,2,1), 256, 0, stream>>>(ch, attrv, attr_b, 3072, 3072, 0);
        cast_slice<<<dim3(12,256), 256, 0, stream>>>(attrv, avh, avl, 3072, 0, 3072, 3072, 3072, 0);
    }
    // featsT now dead: overlay W2ih + W1ih-mid into region R
    cast_slice<<<dim3(12,4096), 256, 0, stream>>>(l2_Wih, W2ihh, W2ihl, 3072, 0, 3072, 3072, 3072, 0);
    cast_slice<<<dim3(8,4096), 256, 0, stream>>>(l1_Wih, Wmh, Wml, 3584, 1024, 2048, 2048, 2048, 0);
    // base1[b][4096] = mf @ Wih[:,1024:3072].T + (l1_bih + l1_bhh)
    {
        GChunks ch = {};
        ch.c[0] = {Wmh,        Wml,        mfh,        mfl,        2048, 2048, 1024};
        ch.c[1] = {Wmh + 1024, Wml + 1024, mfh + 1024, mfl + 1024, 2048, 2048, 1024};
        gemm_mfma<0><<<dim3(32,2,2), 256, 0, stream>>>(ch, Pbuf, nullptr, 4096, 4096, 4096L*256);
        reduce_rows<<<1024, 256, 0, stream>>>(base1, Pbuf, bihbhh1, 2, 4096L*256, 4096*256, 4095);
    }
    // initial lstm2 on attr_v (h2 = 0)
    {
        GChunks ch = {};
        for (int z = 0; z < 3; ++z)
            ch.c[z] = {W2ihh + z*1024, W2ihl + z*1024, avh + z*1024, avl + z*1024, 3072, 3072, 1024};
        gemm_mfma<0><<<dim3(32,2,3), 256, 0, stream>>>(ch, Pbuf, nullptr, 4096, 4096, 4096L*256);
        lstm_fused<<<1024, 256, 0, stream>>>(Pbuf, 3, 4096L*256, bias2, 2, c2, h2h, h2l);
    }

    // static per-step chunk descriptors
    GChunks chG1 = {};
    chG1.c[0] = {W1ph,        W1pl,        h2h,       h2l,       1536, 1024, 512};
    chG1.c[1] = {W1ph + 512,  W1pl + 512,  h2h + 512, h2l + 512, 1536, 1024, 512};
    chG1.c[2] = {W1ph + 1024, W1pl + 1024, wvh,       wvl,       1536, 512,  512};
    chG1.c[3] = {W1hhh,       W1hhl,       h1h,       h1l,       1024, 1024, 512};
    chG1.c[4] = {W1hhh + 512, W1hhl + 512, h1h + 512, h1l + 512, 1024, 1024, 512};
    GChunks chEh = {};
    for (int z = 0; z < 8; ++z)
        chEh.c[z] = {Wahh + z*128, Wahl + z*128, h1h + z*128, h1l + z*128, 1024, 1024, 128};
    GChunks chG2 = {};
    chG2.c[0] = {W2ihh,        W2ihl,        h1h,        h1l,        3072, 1024, 1024};
    chG2.c[1] = {W2ihh + 1024, W2ihl + 1024, vhh,        vhl,        3072, 2048, 1024};
    chG2.c[2] = {W2ihh + 2048, W2ihl + 2048, vhh + 1024, vhl + 1024, 3072, 2048, 1024};
    chG2.c[3] = {W2hhh,        W2hhl,        h2h,        h2l,        1024, 1024, 1024};
    GChunks chPr = {};
    chPr.c[0] = {Wprh,       Wprl,       h2h,       h2l,       1024, 1024, 512};
    chPr.c[1] = {Wprh + 512, Wprl + 512, h2h + 512, h2l + 512, 1024, 1024, 512};

    for (int s = 0; s < NS_; ++s) {
        wv_gather_cast<<<512, 256, 0, stream>>>(sents, emb, wvh, wvl, s);

        gemm_mfma<0><<<dim3(32,2,5), 256, 0, stream>>>(chG1, Pbuf, nullptr, 4096, 4096, 4096L*256);
        lstm_fused<<<1024, 256, 0, stream>>>(Pbuf, 5, 4096L*256, base1, 1, c1, h1h, h1l);

        gemm_mfma<0><<<dim3(4,2,8), 256, 0, stream>>>(chEh, Pbuf, nullptr, 512, 512, 512L*256);
        attention_kernel<<<256, 256, 0, stream>>>(ef, Pbuf, feats, atta_W, atta_b, vhh, vhl);

        gemm_mfma<0><<<dim3(32,2,4), 256, 0, stream>>>(chG2, Pbuf, nullptr, 4096, 4096, 4096L*256);
        lstm_fused<<<1024, 256, 0, stream>>>(Pbuf, 4, 4096L*256, bias2, 2, c2, h2h, h2l);

        gemm_mfma<0><<<dim3(79,2,2), 256, 0, stream>>>(chPr, Pbuf, nullptr, 10000, 10048, 10048L*256);
        reduce_prob<<<2500, 256, 0, stream>>>(Pbuf, prob_b, out, s);

        argmax_kernel<<<256, 256, 0, stream>>>(preds, out, s);
    }
}